// Round 2
// baseline (528.954 us; speedup 1.0000x reference)
//
#include <hip/hip_runtime.h>

#define HID   15
#define TMAIN 1024
#define FUT   64
#define OUTW  (TMAIN + FUT)   // 1088

typedef _Float16 v2h   __attribute__((ext_vector_type(2)));
typedef _Float16 v8h   __attribute__((ext_vector_type(8)));
typedef float    f32x4 __attribute__((ext_vector_type(4)));
typedef int      i32x4 __attribute__((ext_vector_type(4)));

__device__ __forceinline__ float rcp_(float x)  { return __builtin_amdgcn_rcpf(x); }
__device__ __forceinline__ float exp2_(float x) { return __builtin_amdgcn_exp2f(x); }
__device__ __forceinline__ float tanh_(float x) {
    return __builtin_fmaf(2.0f, rcp_(1.0f + exp2_(x * -2.885390081777927f)), -1.0f);
}

template<int I> struct ic { static constexpr int v = I; };
template<int J, int N, class F>
__device__ __forceinline__ void unroll_for(F&& f) {
    if constexpr (J < N) { f(ic<J>{}); unroll_for<J + 1, N>(f); }
}

// ds_swizzle BitMode: dest i reads lane ((i&and)|or)^xor within 32-lane halves.
template<int PAT>
__device__ __forceinline__ int swzi(int x) { return __builtin_amdgcn_ds_swizzle(x, PAT); }
template<int PAT>
__device__ __forceinline__ float swzf(float x) { return __int_as_float(swzi<PAT>(__float_as_int(x))); }

__device__ __forceinline__ int bpermi(int addr, int x) { return __builtin_amdgcn_ds_bpermute(addr, x); }
__device__ __forceinline__ float bpermf(int addr, float x) { return __int_as_float(bpermi(addr, __float_as_int(x))); }

__device__ __forceinline__ v2h pkrtz(float lo, float hi) {
    return __builtin_bit_cast(v2h, __builtin_amdgcn_cvt_pkrtz(lo, hi));
}
__device__ __forceinline__ f32x4 mfma16(v8h a, v8h b, f32x4 c) {
    return __builtin_amdgcn_mfma_f32_16x16x32_f16(a, b, c, 0, 0, 0);
}

// R11: move the 96 half-rate VALU dots to the MFMA pipe.
// Per step: gates[64rows x 16cols] = A[64x32]*B[32x16] + bias, as 4 MFMAs/layer.
//  - W rows interleaved [4*unit+gate] -> each lane's 4 D-regs = i,f,g,o of ONE unit.
//  - B cols 4*cg+s replicate the 4 samples 4x; lane (u,c) consumes MFMA chunk cg
//    (units 4cg..4cg+3) -> 12 cndmask/layer chunk-select, zero cross-lane gather.
//  - One B serves both layers: k0..14=h1, k15=x (L2's A col15=0), k16..30=h2
//    (L1's A cols>=16 are 0). Rebuilt once/step (4 static-addr ds_bpermute) from
//    HP (h1 pairs at even-u lanes, h2 pairs at odd-u lanes; pair7.hi carries x).
//  - A/B fragment k-map (gfx950 two-K-block): elem e -> k = e<4 ? 4u+e : 16+4u+e-4.
//  - out-dot: 16-lane butterfly (swz xor4/8/16 + bperm xor32) -> every lane holds
//    its sample's ov (clean out->x feedback in the future phase).
__global__ __launch_bounds__(256)
__attribute__((amdgpu_waves_per_eu(1, 1)))
void lstm_seq_kernel(const float* __restrict__ input,
                     const float* __restrict__ W_ih1, const float* __restrict__ W_hh1,
                     const float* __restrict__ b_ih1, const float* __restrict__ b_hh1,
                     const float* __restrict__ W_ih2, const float* __restrict__ W_hh2,
                     const float* __restrict__ b_ih2, const float* __restrict__ b_hh2,
                     const float* __restrict__ W_lin, const float* __restrict__ b_lin,
                     float* __restrict__ out)
{
    const int tid  = threadIdx.x;
    const int wq   = tid >> 6;
    const int lane = tid & 63;
    const int u    = lane >> 4;        // K-block row / D row-group
    const int c    = lane & 15;        // MFMA col (B/D) and A-row
    const int s    = c & 3;            // sample within wave
    const int cg   = c >> 2;           // col-group == chunk this lane consumes
    const int b0   = (blockIdx.x * 4 + wq) * 4;

    const float L2E = 1.442695040888963f;
    const float sA[4] = {-L2E, -L2E, -2.0f * L2E, -L2E};

    // ---- static A fragments (scale folded) + bias C fragments ----
    v8h   A1[4], A2[4];
    f32x4 C1[4], C2[4];
    #pragma unroll
    for (int m = 0; m < 4; ++m) {
        #pragma unroll
        for (int e = 0; e < 8; ++e) {
            const int k    = (e < 4) ? (4 * u + e) : (16 + 4 * u + (e - 4));
            const int gate = c & 3;                 // A-row ri = c; gate = ri&3
            const int U    = 4 * m + (c >> 2);      // unit = 4m + (ri>>2)
            float v1 = 0.0f, v2 = 0.0f;
            if (U < HID) {
                const int wr = gate * HID + U;
                if (k < HID)            v1 = W_hh1[wr * HID + k];
                else if (k == HID)      v1 = W_ih1[wr];          // x slot
                if (k < HID)            v2 = W_ih2[wr * HID + k];
                else if (k >= 16 && k < 16 + HID) v2 = W_hh2[wr * HID + (k - 16)];
            }
            A1[m][e] = (_Float16)(sA[gate] * v1);
            A2[m][e] = (_Float16)(sA[gate] * v2);
        }
        #pragma unroll
        for (int r = 0; r < 4; ++r) {               // D row 4u+r -> unit 4m+u, gate r
            const int U = 4 * m + u;
            float bv1 = 0.0f, bv2 = 0.0f;
            if (U < HID) {
                const int wr = r * HID + U;
                bv1 = sA[r] * (b_ih1[wr] + b_hh1[wr]);
                bv2 = sA[r] * (b_ih2[wr] + b_hh2[wr]);
            }
            C1[m][r] = bv1; C2[m][r] = bv2;
        }
    }

    const int   Uh   = 4 * cg + u;                  // unit this lane owns
    const float wl2  = (Uh < HID) ? W_lin[Uh] : 0.0f;
    const float blin = b_lin[0];

    // static bpermute addresses: B-reg q wants pair P=2u+(q&1) of h1 (q<2) / h2 (q>=2)
    int bpa[4];
    #pragma unroll
    for (int q = 0; q < 4; ++q) {
        const int P    = 2 * u + (q & 1);
        const int usrc = (q < 2) ? 2 * (P & 1) : 1 + 2 * (P & 1);
        bpa[q] = (((usrc << 4) + 4 * (P >> 1) + s) << 2);
    }
    const int  a32    = (lane ^ 32) << 2;
    const bool uodd   = (u & 1) != 0;
    const bool cgb0   = (cg & 1) != 0;
    const bool cgb1   = (cg & 2) != 0;
    const bool xmask  = (u == 2) && (cg == 3);      // holder of pair7 = {h1[14], x}
    const int  myslot = (lane >> 2) & 7;

    int B0 = 0, B1 = 0, B2 = 0, B3 = 0;
    int HP = 0;
    float c1v = 0.0f, c2v = 0.0f;

    auto rebuildB = [&]() {
        B0 = bpermi(bpa[0], HP);
        B1 = bpermi(bpa[1], HP);
        B2 = bpermi(bpa[2], HP);
        B3 = bpermi(bpa[3], HP);
    };

    auto step = [&](auto Sc, auto UseOvC, float xvpre, float& oreg) {
        constexpr int  S      = decltype(Sc)::v;
        constexpr bool USE_OV = decltype(UseOvC)::v;

        // ---- layer 1: 4 MFMAs (B holds h1(t-1), x(t); k>=16 ignored by A1) ----
        const v8h Bv = __builtin_bit_cast(v8h, (i32x4){B0, B1, B2, B3});
        f32x4 d0 = mfma16(A1[0], Bv, C1[0]);
        f32x4 d1 = mfma16(A1[1], Bv, C1[1]);
        f32x4 d2 = mfma16(A1[2], Bv, C1[2]);
        f32x4 d3 = mfma16(A1[3], Bv, C1[3]);

        float P0, P1, P2, P3;
        {   // chunk-select by cg
            float t0, t1;
            t0 = cgb0 ? d1[0] : d0[0]; t1 = cgb0 ? d3[0] : d2[0]; P0 = cgb1 ? t1 : t0;
            t0 = cgb0 ? d1[1] : d0[1]; t1 = cgb0 ? d3[1] : d2[1]; P1 = cgb1 ? t1 : t0;
            t0 = cgb0 ? d1[2] : d0[2]; t1 = cgb0 ? d3[2] : d2[2]; P2 = cgb1 ? t1 : t0;
            t0 = cgb0 ? d1[3] : d0[3]; t1 = cgb0 ? d3[3] : d2[3]; P3 = cgb1 ? t1 : t0;
        }

        const float ig = rcp_(1.0f + exp2_(P0));
        const float fg = rcp_(1.0f + exp2_(P1));
        const float gg = __builtin_fmaf(2.0f, rcp_(1.0f + exp2_(P2)), -1.0f);
        const float og = rcp_(1.0f + exp2_(P3));
        c1v = __builtin_fmaf(fg, c1v, ig * gg);
        const float h1n = og * tanh_(c1v);

        // ---- pack h1 pairs (even-u lanes valid), inject x(t+1) at pair7.hi ----
        const float prt1 = swzf<0x401F>(h1n);                  // partner h1 (lane^16)
        const float hi1  = xmask ? xvpre : prt1;
        const int   h1p  = __builtin_bit_cast(int, pkrtz(h1n, hi1));
        HP = uodd ? HP : h1p;
        rebuildB();                                            // B <- {h1(t), x(t+1), h2(t-1)}

        // ---- layer 2: 4 MFMAs (k15 ignored by A2) ----
        const v8h Bv2 = __builtin_bit_cast(v8h, (i32x4){B0, B1, B2, B3});
        f32x4 e0 = mfma16(A2[0], Bv2, C2[0]);
        f32x4 e1 = mfma16(A2[1], Bv2, C2[1]);
        f32x4 e2 = mfma16(A2[2], Bv2, C2[2]);
        f32x4 e3 = mfma16(A2[3], Bv2, C2[3]);

        float Q0, Q1, Q2, Q3;
        {
            float t0, t1;
            t0 = cgb0 ? e1[0] : e0[0]; t1 = cgb0 ? e3[0] : e2[0]; Q0 = cgb1 ? t1 : t0;
            t0 = cgb0 ? e1[1] : e0[1]; t1 = cgb0 ? e3[1] : e2[1]; Q1 = cgb1 ? t1 : t0;
            t0 = cgb0 ? e1[2] : e0[2]; t1 = cgb0 ? e3[2] : e2[2]; Q2 = cgb1 ? t1 : t0;
            t0 = cgb0 ? e1[3] : e0[3]; t1 = cgb0 ? e3[3] : e2[3]; Q3 = cgb1 ? t1 : t0;
        }

        const float i2 = rcp_(1.0f + exp2_(Q0));
        const float f2 = rcp_(1.0f + exp2_(Q1));
        const float g2 = __builtin_fmaf(2.0f, rcp_(1.0f + exp2_(Q2)), -1.0f);
        const float o2 = rcp_(1.0f + exp2_(Q3));
        c2v = __builtin_fmaf(f2, c2v, i2 * g2);
        const float h2n = o2 * tanh_(c2v);

        // ---- out = <W_lin, h2> + b: butterfly over lanes sharing s ----
        float pv = wl2 * h2n;
        pv += swzf<0x101F>(pv);                                // xor 4
        pv += swzf<0x201F>(pv);                                // xor 8
        pv += swzf<0x401F>(pv);                                // xor 16
        pv += bpermf(a32, pv);                                 // xor 32
        const float ov = pv + blin;
        oreg = (myslot == S) ? ov : oreg;

        // ---- pack h2 pairs into HP (odd-u lanes) ----
        const float prt2 = swzf<0x401F>(h2n);
        const int   h2p  = __builtin_bit_cast(int, pkrtz(prt2, h2n));
        HP = uodd ? h2p : HP;

        if constexpr (USE_OV) {
            // x(t+1) = ov: patch HP pair7.hi (xmask lane owns h1[14]) + refresh B1
            const int hx = __builtin_bit_cast(int, pkrtz(h1n, ov));
            HP = xmask ? hx : HP;
            B1 = bpermi(bpa[1], HP);
        }
    };

    const size_t inb  = (size_t)(b0 + s) * TMAIN + myslot;
    const size_t outb = (size_t)(b0 + s) * OUTW  + myslot;

    float xcur = input[inb];                                   // slots 0..7, chunk 0
    {   // prologue: h=0, x(0) into pair7.hi
        const float x0 = swzf<3>(xcur);                        // slot-0 broadcast
        const int p1 = __builtin_bit_cast(int, pkrtz(0.0f, xmask ? x0 : 0.0f));
        HP = uodd ? 0 : p1;
        rebuildB();
    }

    // ---- main: 128 chunks of 8 steps; x prefetched one chunk ahead ----
    #pragma unroll 1
    for (int ch = 0; ch < TMAIN / 8; ++ch) {
        const bool last = (ch == TMAIN / 8 - 1);
        const float xnext = input[inb + (size_t)(last ? ch : ch + 1) * 8];
        float oreg = 0.0f;
        unroll_for<0, 8>([&](auto sc) {
            constexpr int sI = decltype(sc)::v;
            if constexpr (sI < 7) {
                step(sc, ic<0>{}, swzf<((sI + 1) * 128) | 3>(xcur), oreg);
            } else {
                if (last) step(sc, ic<1>{}, 0.0f, oreg);
                else      step(sc, ic<0>{}, swzf<3>(xnext), oreg);
            }
        });
        if (lane < 32) out[outb + (size_t)ch * 8] = oreg;
        xcur = xnext;
    }

    // ---- future: x = previous out (USE_OV patches pair7.hi with ov) ----
    #pragma unroll 1
    for (int fc = 0; fc < FUT / 8; ++fc) {
        float oreg = 0.0f;
        unroll_for<0, 8>([&](auto sc) {
            step(sc, ic<1>{}, 0.0f, oreg);
        });
        if (lane < 32) out[outb + TMAIN + (size_t)fc * 8] = oreg;
    }
}

extern "C" void kernel_launch(void* const* d_in, const int* in_sizes, int n_in,
                              void* d_out, int out_size, void* d_ws, size_t ws_size,
                              hipStream_t stream)
{
    const float* input = (const float*)d_in[0];
    const float* W_ih1 = (const float*)d_in[1];
    const float* W_hh1 = (const float*)d_in[2];
    const float* b_ih1 = (const float*)d_in[3];
    const float* b_hh1 = (const float*)d_in[4];
    const float* W_ih2 = (const float*)d_in[5];
    const float* W_hh2 = (const float*)d_in[6];
    const float* b_ih2 = (const float*)d_in[7];
    const float* b_hh2 = (const float*)d_in[8];
    const float* W_lin = (const float*)d_in[9];
    const float* b_lin = (const float*)d_in[10];
    // d_in[11] = future (=64), compiled in as FUT

    // 4096 batches / (4 per wave * 4 waves per block) = 256 blocks
    lstm_seq_kernel<<<256, 256, 0, stream>>>(
        input, W_ih1, W_hh1, b_ih1, b_hh1,
        W_ih2, W_hh2, b_ih2, b_hh2, W_lin, b_lin,
        (float*)d_out);
}

// Round 5
// 502.627 us; speedup vs baseline: 1.0524x; 1.0524x over previous
//
#include <hip/hip_runtime.h>

#define HID   15
#define TMAIN 1024
#define FUT   64
#define OUTW  (TMAIN + FUT)   // 1088

typedef _Float16 v2h   __attribute__((ext_vector_type(2)));
typedef _Float16 v8h   __attribute__((ext_vector_type(8)));
typedef float    f32x4 __attribute__((ext_vector_type(4)));
typedef int      i32x4 __attribute__((ext_vector_type(4)));

__device__ __forceinline__ float rcp_(float x)  { return __builtin_amdgcn_rcpf(x); }
__device__ __forceinline__ float exp2_(float x) { return __builtin_amdgcn_exp2f(x); }
__device__ __forceinline__ float tanh_(float x) {
    return __builtin_fmaf(2.0f, rcp_(1.0f + exp2_(x * -2.885390081777927f)), -1.0f);
}

template<int I> struct ic { static constexpr int v = I; };
template<int J, int N, class F>
__device__ __forceinline__ void unroll_for(F&& f) {
    if constexpr (J < N) { f(ic<J>{}); unroll_for<J + 1, N>(f); }
}

// ds_swizzle BitMode: dest i reads lane ((i&and)|or)^xor within 32-lane halves.
template<int PAT>
__device__ __forceinline__ int swzi(int x) { return __builtin_amdgcn_ds_swizzle(x, PAT); }
template<int PAT>
__device__ __forceinline__ float swzf(float x) { return __int_as_float(swzi<PAT>(__float_as_int(x))); }

__device__ __forceinline__ int bpermi(int addr, int x) { return __builtin_amdgcn_ds_bpermute(addr, x); }
__device__ __forceinline__ float bpermf(int addr, float x) { return __int_as_float(bpermi(addr, __float_as_int(x))); }

__device__ __forceinline__ v2h pkrtz(float lo, float hi) {
    return __builtin_bit_cast(v2h, __builtin_amdgcn_cvt_pkrtz(lo, hi));
}
__device__ __forceinline__ f32x4 mfma16(v8h a, v8h b, f32x4 c) {
    return __builtin_amdgcn_mfma_f32_16x16x32_f16(a, b, c, 0, 0, 0);
}

// R13 = R12's half-step pipeline on R11's VERIFIED lane-exchange primitives.
// R12 failed (absmax 6e-2) -- prime suspect: v_permlane16_swap_b32 direction
// (own vs partner select) in packEven/packOdd.  outdot's use was
// direction-insensitive, but all permlane asm is dropped anyway to isolate
// the pipeline hypothesis on known-good ops (ds_swizzle xor / ds_bpermute).
//  Pipeline (unchanged from R12):
//   B = {h1(t), x(t+1), h2(t-1)} feeds BOTH L2(t) and L1(t+1) -> 8 MFMAs
//   issued together, one pack+rebuild per step, L2(t)/L1(t+1) trans chains
//   independent (mutually latency-hiding).  Future phase stays serial
//   (out->x feedback).
__global__ __launch_bounds__(256)
__attribute__((amdgpu_waves_per_eu(1, 1)))
void lstm_seq_kernel(const float* __restrict__ input,
                     const float* __restrict__ W_ih1, const float* __restrict__ W_hh1,
                     const float* __restrict__ b_ih1, const float* __restrict__ b_hh1,
                     const float* __restrict__ W_ih2, const float* __restrict__ W_hh2,
                     const float* __restrict__ b_ih2, const float* __restrict__ b_hh2,
                     const float* __restrict__ W_lin, const float* __restrict__ b_lin,
                     float* __restrict__ out)
{
    const int tid  = threadIdx.x;
    const int wq   = tid >> 6;
    const int lane = tid & 63;
    const int u    = lane >> 4;        // K-block row / D row-group
    const int c    = lane & 15;        // MFMA col (B/D) and A-row
    const int s    = c & 3;            // sample within wave
    const int cg   = c >> 2;           // col-group == chunk this lane consumes
    const int b0   = (blockIdx.x * 4 + wq) * 4;

    const float L2E = 1.442695040888963f;
    const float sA[4] = {-L2E, -L2E, -2.0f * L2E, -L2E};

    // ---- static A fragments (scale folded) + bias C fragments ----
    v8h   A1[4], A2[4];
    f32x4 C1[4], C2[4];
    #pragma unroll
    for (int m = 0; m < 4; ++m) {
        #pragma unroll
        for (int e = 0; e < 8; ++e) {
            const int k    = (e < 4) ? (4 * u + e) : (16 + 4 * u + (e - 4));
            const int gate = c & 3;                 // A-row ri = c; gate = ri&3
            const int U    = 4 * m + (c >> 2);      // unit = 4m + (ri>>2)
            float v1 = 0.0f, v2 = 0.0f;
            if (U < HID) {
                const int wr = gate * HID + U;
                if (k < HID)            v1 = W_hh1[wr * HID + k];
                else if (k == HID)      v1 = W_ih1[wr];          // x slot
                if (k < HID)            v2 = W_ih2[wr * HID + k];
                else if (k >= 16 && k < 16 + HID) v2 = W_hh2[wr * HID + (k - 16)];
            }
            A1[m][e] = (_Float16)(sA[gate] * v1);
            A2[m][e] = (_Float16)(sA[gate] * v2);
        }
        #pragma unroll
        for (int r = 0; r < 4; ++r) {               // D row 4u+r -> unit 4m+u, gate r
            const int U = 4 * m + u;
            float bv1 = 0.0f, bv2 = 0.0f;
            if (U < HID) {
                const int wr = r * HID + U;
                bv1 = sA[r] * (b_ih1[wr] + b_hh1[wr]);
                bv2 = sA[r] * (b_ih2[wr] + b_hh2[wr]);
            }
            C1[m][r] = bv1; C2[m][r] = bv2;
        }
    }

    const int   Uh   = 4 * cg + u;                  // unit this lane owns
    const float wl2  = (Uh < HID) ? W_lin[Uh] : 0.0f;
    const float blin = b_lin[0];

    // static bpermute addresses: B-reg q wants pair P=2u+(q&1) of h1 (q<2) / h2 (q>=2)
    int bpa[4];
    #pragma unroll
    for (int q = 0; q < 4; ++q) {
        const int P    = 2 * u + (q & 1);
        const int usrc = (q < 2) ? 2 * (P & 1) : 1 + 2 * (P & 1);
        bpa[q] = (((usrc << 4) + 4 * (P >> 1) + s) << 2);
    }
    const int  a32    = (lane ^ 32) << 2;
    const bool uodd   = (u & 1) != 0;
    const bool cgb0   = (cg & 1) != 0;
    const bool cgb1   = (cg & 2) != 0;
    const bool xmask  = (u == 2) && (cg == 3);      // holder of pair7 = {h1[14], x}
    const int  myslot = (lane >> 2) & 7;

    int B0 = 0, B1 = 0, B2 = 0, B3 = 0;
    int HP = 0;
    float c1v = 0.0f, c2v = 0.0f, h1cur = 0.0f;

    auto rebuildB = [&]() {
        B0 = bpermi(bpa[0], HP);
        B1 = bpermi(bpa[1], HP);
        B2 = bpermi(bpa[2], HP);
        B3 = bpermi(bpa[3], HP);
    };
    auto makeB = [&]() -> v8h {
        return __builtin_bit_cast(v8h, (i32x4){B0, B1, B2, B3});
    };

    auto sel4 = [&](const f32x4& a0, const f32x4& a1, const f32x4& a2, const f32x4& a3,
                    float& r0, float& r1, float& r2, float& r3) {
        float t0, t1;
        t0 = cgb0 ? a1[0] : a0[0]; t1 = cgb0 ? a3[0] : a2[0]; r0 = cgb1 ? t1 : t0;
        t0 = cgb0 ? a1[1] : a0[1]; t1 = cgb0 ? a3[1] : a2[1]; r1 = cgb1 ? t1 : t0;
        t0 = cgb0 ? a1[2] : a0[2]; t1 = cgb0 ? a3[2] : a2[2]; r2 = cgb1 ? t1 : t0;
        t0 = cgb0 ? a1[3] : a0[3]; t1 = cgb0 ? a3[3] : a2[3]; r3 = cgb1 ? t1 : t0;
    };

    // out-dot: sum over the 16 lanes of this sample class (VERIFIED R11 chain).
    auto outdot = [&](float h) -> float {
        float pv = wl2 * h;
        pv += swzf<0x101F>(pv);                      // xor 4
        pv += swzf<0x201F>(pv);                      // xor 8
        pv += swzf<0x401F>(pv);                      // xor 16
        pv += bpermf(a32, pv);                       // xor 32
        return pv + blin;
    };

    // pack h1 pairs into HP (even-u rows); pair7.hi carries x  (VERIFIED R11 ops)
    auto packEven = [&](float h, float xv) {
        const float prt = swzf<0x401F>(h);           // partner (lane^16)
        const float hi1 = xmask ? xv : prt;
        const int p = __builtin_bit_cast(int, pkrtz(h, hi1));
        HP = uodd ? HP : p;
    };
    // pack h2 pairs into HP (odd-u rows)
    auto packOdd = [&](float h) {
        const float prt = swzf<0x401F>(h);
        const int p = __builtin_bit_cast(int, pkrtz(prt, h));
        HP = uodd ? p : HP;
    };

    // pipelined iteration t: B = {h1(t), x(t+1), h2(t-1)}.
    // computes h2(t) (L2) and h1(t+1) (L1) together; injects x(t+2).
    auto iterP = [&](auto Sc, float xv2, float& oreg) {
        constexpr int S = decltype(Sc)::v;
        const v8h Bv = makeB();
        f32x4 e0 = mfma16(A2[0], Bv, C2[0]);
        f32x4 e1 = mfma16(A2[1], Bv, C2[1]);
        f32x4 e2 = mfma16(A2[2], Bv, C2[2]);
        f32x4 e3 = mfma16(A2[3], Bv, C2[3]);
        f32x4 d0 = mfma16(A1[0], Bv, C1[0]);
        f32x4 d1 = mfma16(A1[1], Bv, C1[1]);
        f32x4 d2 = mfma16(A1[2], Bv, C1[2]);
        f32x4 d3 = mfma16(A1[3], Bv, C1[3]);

        float Q0, Q1, Q2, Q3, P0, P1, P2, P3;
        sel4(e0, e1, e2, e3, Q0, Q1, Q2, Q3);
        sel4(d0, d1, d2, d3, P0, P1, P2, P3);

        // L2 acts -> h2(t)
        const float i2 = rcp_(1.0f + exp2_(Q0));
        const float f2 = rcp_(1.0f + exp2_(Q1));
        const float g2 = __builtin_fmaf(2.0f, rcp_(1.0f + exp2_(Q2)), -1.0f);
        const float o2 = rcp_(1.0f + exp2_(Q3));
        c2v = __builtin_fmaf(f2, c2v, i2 * g2);
        const float h2n = o2 * tanh_(c2v);

        // L1 acts -> h1(t+1)   (independent chain, overlaps L2's)
        const float ig = rcp_(1.0f + exp2_(P0));
        const float fg = rcp_(1.0f + exp2_(P1));
        const float gg = __builtin_fmaf(2.0f, rcp_(1.0f + exp2_(P2)), -1.0f);
        const float og = rcp_(1.0f + exp2_(P3));
        c1v = __builtin_fmaf(fg, c1v, ig * gg);
        const float h1n = og * tanh_(c1v);
        h1cur = h1n;

        packEven(h1n, xv2);
        packOdd(h2n);
        rebuildB();                                  // B -> {h1(t+1), x(t+2), h2(t)}

        const float ov = outdot(h2n);                // off critical path
        oreg = (myslot == S) ? ov : oreg;
    };

    // serial step (future phase): B = {h1(t-1), x(t)=ov(t-1), h2(t-1)}
    auto stepS = [&](auto Sc, float& oreg) {
        constexpr int S = decltype(Sc)::v;
        const v8h Bv = makeB();
        f32x4 d0 = mfma16(A1[0], Bv, C1[0]);
        f32x4 d1 = mfma16(A1[1], Bv, C1[1]);
        f32x4 d2 = mfma16(A1[2], Bv, C1[2]);
        f32x4 d3 = mfma16(A1[3], Bv, C1[3]);
        float P0, P1, P2, P3;
        sel4(d0, d1, d2, d3, P0, P1, P2, P3);
        const float ig = rcp_(1.0f + exp2_(P0));
        const float fg = rcp_(1.0f + exp2_(P1));
        const float gg = __builtin_fmaf(2.0f, rcp_(1.0f + exp2_(P2)), -1.0f);
        const float og = rcp_(1.0f + exp2_(P3));
        c1v = __builtin_fmaf(fg, c1v, ig * gg);
        const float h1n = og * tanh_(c1v);

        packEven(h1n, 0.0f);                          // x patched after ov known
        rebuildB();

        const v8h Bv2 = makeB();
        f32x4 e0 = mfma16(A2[0], Bv2, C2[0]);
        f32x4 e1 = mfma16(A2[1], Bv2, C2[1]);
        f32x4 e2 = mfma16(A2[2], Bv2, C2[2]);
        f32x4 e3 = mfma16(A2[3], Bv2, C2[3]);
        float Q0, Q1, Q2, Q3;
        sel4(e0, e1, e2, e3, Q0, Q1, Q2, Q3);
        const float i2 = rcp_(1.0f + exp2_(Q0));
        const float f2 = rcp_(1.0f + exp2_(Q1));
        const float g2 = __builtin_fmaf(2.0f, rcp_(1.0f + exp2_(Q2)), -1.0f);
        const float o2 = rcp_(1.0f + exp2_(Q3));
        c2v = __builtin_fmaf(f2, c2v, i2 * g2);
        const float h2n = o2 * tanh_(c2v);

        const float ov = outdot(h2n);
        oreg = (myslot == S) ? ov : oreg;

        packOdd(h2n);
        HP = xmask ? __builtin_bit_cast(int, pkrtz(h1n, ov)) : HP;  // x(t+1)=ov
        B1 = bpermi(bpa[1], HP);
    };

    const size_t inb  = (size_t)(b0 + s) * TMAIN + myslot;
    const size_t outb = (size_t)(b0 + s) * OUTW  + myslot;

    float xcur = input[inb];

    // ---- prologue: h(-1)=0; compute h1(0); B_0 = {h1(0), x(1), 0} ----
    {
        const float x0 = swzf<3>(xcur);              // slot-0 broadcast
        HP = uodd ? 0 : __builtin_bit_cast(int, pkrtz(0.0f, xmask ? x0 : 0.0f));
        rebuildB();
        const v8h Bv = makeB();
        f32x4 d0 = mfma16(A1[0], Bv, C1[0]);
        f32x4 d1 = mfma16(A1[1], Bv, C1[1]);
        f32x4 d2 = mfma16(A1[2], Bv, C1[2]);
        f32x4 d3 = mfma16(A1[3], Bv, C1[3]);
        float P0, P1, P2, P3;
        sel4(d0, d1, d2, d3, P0, P1, P2, P3);
        const float ig = rcp_(1.0f + exp2_(P0));
        const float fg = rcp_(1.0f + exp2_(P1));
        const float gg = __builtin_fmaf(2.0f, rcp_(1.0f + exp2_(P2)), -1.0f);
        const float og = rcp_(1.0f + exp2_(P3));
        c1v = __builtin_fmaf(fg, c1v, ig * gg);
        const float h1n = og * tanh_(c1v);
        h1cur = h1n;
        const float x1 = swzf<0x83>(xcur);           // slot-1 broadcast
        packEven(h1n, x1);
        rebuildB();
    }

    // ---- main: 127 full chunks of 8 pipelined iters ----
    #pragma unroll 1
    for (int ch = 0; ch < TMAIN / 8 - 1; ++ch) {
        const float xnext = input[inb + (size_t)(ch + 1) * 8];
        float oreg = 0.0f;
        unroll_for<0, 8>([&](auto sc) {
            constexpr int sI = decltype(sc)::v;
            if constexpr (sI < 6) {
                iterP(sc, swzf<((sI + 2) * 128) | 3>(xcur), oreg);
            } else if constexpr (sI == 6) {
                iterP(sc, swzf<3>(xnext), oreg);             // next-chunk slot 0
            } else {
                iterP(sc, swzf<0x83>(xnext), oreg);          // next-chunk slot 1
            }
        });
        if (lane < 32) out[outb + (size_t)ch * 8] = oreg;
        xcur = xnext;
    }

    // ---- final chunk: 7 pipelined iters + L2-only epilogue (t=1023) ----
    {
        float oreg = 0.0f;
        unroll_for<0, 7>([&](auto sc) {
            constexpr int sI = decltype(sc)::v;
            if constexpr (sI < 6) {
                iterP(sc, swzf<((sI + 2) * 128) | 3>(xcur), oreg);
            } else {
                iterP(sc, 0.0f, oreg);               // x(1024)=ov(1023), patched below
            }
        });
        // epilogue: B = {h1(1023), placeholder-x, h2(1022)} -> h2(1023)
        const v8h Bv = makeB();
        f32x4 e0 = mfma16(A2[0], Bv, C2[0]);
        f32x4 e1 = mfma16(A2[1], Bv, C2[1]);
        f32x4 e2 = mfma16(A2[2], Bv, C2[2]);
        f32x4 e3 = mfma16(A2[3], Bv, C2[3]);
        float Q0, Q1, Q2, Q3;
        sel4(e0, e1, e2, e3, Q0, Q1, Q2, Q3);
        const float i2 = rcp_(1.0f + exp2_(Q0));
        const float f2 = rcp_(1.0f + exp2_(Q1));
        const float g2 = __builtin_fmaf(2.0f, rcp_(1.0f + exp2_(Q2)), -1.0f);
        const float o2 = rcp_(1.0f + exp2_(Q3));
        c2v = __builtin_fmaf(f2, c2v, i2 * g2);
        const float h2n = o2 * tanh_(c2v);
        const float ov = outdot(h2n);
        oreg = (myslot == 7) ? ov : oreg;
        packOdd(h2n);
        HP = xmask ? __builtin_bit_cast(int, pkrtz(h1cur, ov)) : HP;  // x(1024)=ov(1023)
        rebuildB();                                   // B = {h1(1023), ov, h2(1023)}
        if (lane < 32) out[outb + (size_t)(TMAIN / 8 - 1) * 8] = oreg;
    }

    // ---- future: 64 serial steps, x = previous out ----
    #pragma unroll 1
    for (int fc = 0; fc < FUT / 8; ++fc) {
        float oreg = 0.0f;
        unroll_for<0, 8>([&](auto sc) {
            stepS(sc, oreg);
        });
        if (lane < 32) out[outb + TMAIN + (size_t)fc * 8] = oreg;
    }
}

extern "C" void kernel_launch(void* const* d_in, const int* in_sizes, int n_in,
                              void* d_out, int out_size, void* d_ws, size_t ws_size,
                              hipStream_t stream)
{
    const float* input = (const float*)d_in[0];
    const float* W_ih1 = (const float*)d_in[1];
    const float* W_hh1 = (const float*)d_in[2];
    const float* b_ih1 = (const float*)d_in[3];
    const float* b_hh1 = (const float*)d_in[4];
    const float* W_ih2 = (const float*)d_in[5];
    const float* W_hh2 = (const float*)d_in[6];
    const float* b_ih2 = (const float*)d_in[7];
    const float* b_hh2 = (const float*)d_in[8];
    const float* W_lin = (const float*)d_in[9];
    const float* b_lin = (const float*)d_in[10];
    // d_in[11] = future (=64), compiled in as FUT

    // 4096 batches / (4 per wave * 4 waves per block) = 256 blocks
    lstm_seq_kernel<<<256, 256, 0, stream>>>(
        input, W_ih1, W_hh1, b_ih1, b_hh1,
        W_ih2, W_hh2, b_ih2, b_hh2, W_lin, b_lin,
        (float*)d_out);
}

// Round 8
// 467.792 us; speedup vs baseline: 1.1307x; 1.0745x over previous
//
#include <hip/hip_runtime.h>

#define HID   15
#define TMAIN 1024
#define FUT   64
#define OUTW  (TMAIN + FUT)   // 1088

typedef _Float16 v2h   __attribute__((ext_vector_type(2)));
typedef _Float16 v8h   __attribute__((ext_vector_type(8)));
typedef float    f32x4 __attribute__((ext_vector_type(4)));
typedef int      i32x4 __attribute__((ext_vector_type(4)));

__device__ __forceinline__ float rcp_(float x)  { return __builtin_amdgcn_rcpf(x); }
__device__ __forceinline__ float exp2_(float x) { return __builtin_amdgcn_exp2f(x); }
__device__ __forceinline__ float tanh_(float x) {
    return __builtin_fmaf(2.0f, rcp_(1.0f + exp2_(x * -2.885390081777927f)), -1.0f);
}

template<int I> struct ic { static constexpr int v = I; };
template<int J, int N, class F>
__device__ __forceinline__ void unroll_for(F&& f) {
    if constexpr (J < N) { f(ic<J>{}); unroll_for<J + 1, N>(f); }
}

// ds_swizzle BitMode: dest i reads lane ((i&and)|or)^xor within 32-lane halves.
template<int PAT>
__device__ __forceinline__ int swzi(int x) { return __builtin_amdgcn_ds_swizzle(x, PAT); }
template<int PAT>
__device__ __forceinline__ float swzf(float x) { return __int_as_float(swzi<PAT>(__float_as_int(x))); }

__device__ __forceinline__ int bpermi(int addr, int x) { return __builtin_amdgcn_ds_bpermute(addr, x); }
__device__ __forceinline__ float bpermf(int addr, float x) { return __int_as_float(bpermi(addr, __float_as_int(x))); }

// DPP: row_shl:n = 0x100+n, row_shr:n = 0x110+n (16-lane rows, bound_ctrl 0-fill)
template<int CTRL>
__device__ __forceinline__ int dppi(int x) {
    return __builtin_amdgcn_update_dpp(0, x, CTRL, 0xF, 0xF, true);
}

__device__ __forceinline__ v2h pkrtz(float lo, float hi) {
    return __builtin_bit_cast(v2h, __builtin_amdgcn_cvt_pkrtz(lo, hi));
}
__device__ __forceinline__ f32x4 mfma16(v8h a, v8h b, f32x4 c) {
    return __builtin_amdgcn_mfma_f32_16x16x32_f16(a, b, c, 0, 0, 0);
}
template<int I>
__device__ __forceinline__ float xel(const f32x4& a, const f32x4& b) {
    if constexpr (I < 4) return a[I]; else return b[I - 4];
}

// R15 = R14 with the slots() mux tree FIXED (R14's sole bug, desk-verified
// against the full 16-cell truth table s_j = R[(cg-j)&3]).
// R14 recap: zero-DS main loop.  Chunk m = GATE m, A-rows = units.  Lane
// (u,4cg+s) selects reg r=cg -> owns unit 4u+cg, sample s.  B-fragment needs
// cols {s,4+s,8+s,12+s} of its OWN row -> 3 row-rotations (row_shr|row_shl
// DPP) + 8 cndmask + 2 pkrtz per layer.  No ds_swizzle / ds_bpermute.
//  - out-dot via MFMA: W_lin in A2 chunk3 row15 (k16..30), blin in C2[3][3]
//    -> e3[3] (u=3 lanes) = ov(t-1).  Butterfly only in future/epilogue.
//  - x per-lane registers (prefetched one chunk ahead).
//  - ov lag: iter t produces ov(t-1); chunk stores trail by one iter.
// Pipeline (R13, verified): B(t)={h1(t),x(t+1),h2(t-1)} feeds L2(t) AND
// L1(t+1); 8 MFMAs issued together.  Future phase serial (out->x feedback).
__global__ __launch_bounds__(256)
__attribute__((amdgpu_waves_per_eu(1, 1)))
void lstm_seq_kernel(const float* __restrict__ input,
                     const float* __restrict__ W_ih1, const float* __restrict__ W_hh1,
                     const float* __restrict__ b_ih1, const float* __restrict__ b_hh1,
                     const float* __restrict__ W_ih2, const float* __restrict__ W_hh2,
                     const float* __restrict__ b_ih2, const float* __restrict__ b_hh2,
                     const float* __restrict__ W_lin, const float* __restrict__ b_lin,
                     float* __restrict__ out)
{
    const int tid  = threadIdx.x;
    const int wq   = tid >> 6;
    const int lane = tid & 63;
    const int u    = lane >> 4;        // K-block row / D row-group
    const int c    = lane & 15;        // MFMA col (B/D) and A-row
    const int s    = c & 3;            // sample within wave
    const int cg   = c >> 2;           // col-group == owned-unit offset
    const int b0   = (blockIdx.x * 4 + wq) * 4;

    const float L2E = 1.442695040888963f;
    const float sA[4] = {-L2E, -L2E, -2.0f * L2E, -L2E};
    const float blin = b_lin[0];

    // ---- static A fragments (chunk = gate, rows = units) + bias C ----
    v8h   A1[4], A2[4];
    f32x4 C1[4], C2[4];
    #pragma unroll
    for (int m = 0; m < 4; ++m) {
        #pragma unroll
        for (int e = 0; e < 8; ++e) {
            const int k = (e < 4) ? (4 * u + e) : (16 + 4 * u + (e - 4));
            float v1 = 0.0f, v2 = 0.0f;
            if (c < HID) {
                const int wr = m * HID + c;            // gate m, unit c
                if (k < HID)       { v1 = W_hh1[wr * HID + k]; v2 = W_ih2[wr * HID + k]; }
                else if (k == HID) { v1 = W_ih1[wr]; }                     // x slot
                else if (k >= 16 && k < 16 + HID) { v2 = W_hh2[wr * HID + (k - 16)]; }
            }
            float a2v = sA[m] * v2;
            if (c == 15 && m == 3 && k >= 16 && k < 16 + HID)
                a2v = W_lin[k - 16];                   // out-row (unscaled)
            A1[m][e] = (_Float16)(sA[m] * v1);
            A2[m][e] = (_Float16)a2v;
        }
        #pragma unroll
        for (int r = 0; r < 4; ++r) {                  // D row 4u+r = unit 4u+r, gate m
            const int U = 4 * u + r;
            float bv1 = 0.0f, bv2 = 0.0f;
            if (U < HID) {
                bv1 = sA[m] * (b_ih1[m * HID + U] + b_hh1[m * HID + U]);
                bv2 = sA[m] * (b_ih2[m * HID + U] + b_hh2[m * HID + U]);
            }
            if (u == 3 && m == 3 && r == 3) bv2 = blin;   // out-row bias
            C1[m][r] = bv1; C2[m][r] = bv2;
        }
    }

    const int   Uown = 4 * u + cg;                     // owned unit
    const float wl2  = (Uown < HID) ? W_lin[Uown] : 0.0f;

    const bool cgb0  = (cg & 1) != 0;
    const bool cgb1  = (cg & 2) != 0;
    const bool u3b   = (u == 3);
    const bool pad15 = u3b && (cg == 3);
    const int  a32   = (lane ^ 32) << 2;

    int B0 = 0, B1 = 0, B2 = 0, B3 = 0;
    float c1v = 0.0f, c2v = 0.0f;
    float oA = 0.0f, oB = 0.0f;

    auto makeB = [&]() -> v8h {
        return __builtin_bit_cast(v8h, (i32x4){B0, B1, B2, B3});
    };

    // P_m = q_m[cg] (constant-index cndmask tree)
    auto gsel = [&](const f32x4& q0, const f32x4& q1, const f32x4& q2, const f32x4& q3,
                    float& g0, float& g1, float& g2, float& g3) {
        auto pick = [&](const f32x4& q) -> float {
            const float t0 = cgb0 ? q[1] : q[0];
            const float t1 = cgb0 ? q[3] : q[2];
            return cgb1 ? t1 : t0;
        };
        g0 = pick(q0); g1 = pick(q1); g2 = pick(q2); g3 = pick(q3);
    };

    auto acts = [&](float g0, float g1, float g2, float g3, float& cv) -> float {
        const float i_ = rcp_(1.0f + exp2_(g0));
        const float f_ = rcp_(1.0f + exp2_(g1));
        const float gg = __builtin_fmaf(2.0f, rcp_(1.0f + exp2_(g2)), -1.0f);
        const float o_ = rcp_(1.0f + exp2_(g3));
        cv = __builtin_fmaf(f_, cv, i_ * gg);
        return o_ * tanh_(cv);
    };

    // slots: s_j = h of unit 4u+j.  R[t] = gather from col (i-4t)&15 holds
    // h[4u + ((cg-t)&3)]  =>  s_j = R[(cg-j)&3].  FIXED tree (R14 bug):
    //  A0=cgb0?r4:h, A1=cgb0?r12:r8, A2=cgb0?h:r12, A3=cgb0?r8:r4
    //  s0=cgb1?A1:A0  s1=cgb1?A3:A2  s2=cgb1?A0:A1  s3=cgb1?A2:A3
    auto slots = [&](float h, float& s0, float& s1, float& s2, float& s3) {
        const int hb = __float_as_int(h);
        const float r4  = __int_as_float(dppi<0x114>(hb) | dppi<0x10C>(hb)); // ror4
        const float r8  = __int_as_float(dppi<0x118>(hb) | dppi<0x108>(hb)); // ror8
        const float r12 = __int_as_float(dppi<0x11C>(hb) | dppi<0x104>(hb)); // ror12
        const float A0 = cgb0 ? r4  : h;
        const float A1 = cgb0 ? r12 : r8;
        const float A2 = cgb0 ? h   : r12;
        const float A3 = cgb0 ? r8  : r4;
        s0 = cgb1 ? A1 : A0;
        s1 = cgb1 ? A3 : A2;
        s2 = cgb1 ? A0 : A1;
        s3 = cgb1 ? A2 : A3;
    };

    auto pack01 = [&](float h1n, float xv) {           // B regs 0,1 <- h1 (+x at u3)
        float s0, s1, s2, s3; slots(h1n, s0, s1, s2, s3);
        B0 = __builtin_bit_cast(int, pkrtz(s0, s1));
        B1 = __builtin_bit_cast(int, pkrtz(s2, u3b ? xv : s3));
    };
    auto pack23 = [&](float h2n) {                     // B regs 2,3 <- h2
        float s0, s1, s2, s3; slots(h2n, s0, s1, s2, s3);
        B2 = __builtin_bit_cast(int, pkrtz(s0, s1));
        B3 = __builtin_bit_cast(int, pkrtz(s2, s3));
    };

    auto stash = [&](auto SigC, float ov) {            // slot sig -> oA/oB at cg==sig&3
        constexpr int SIG = decltype(SigC)::v;
        const bool own = (cg == (SIG & 3));
        if constexpr (SIG < 4) oA = own ? ov : oA;
        else                   oB = own ? ov : oB;
    };

    const size_t xadr   = (size_t)(b0 + s) * TMAIN;
    const size_t outb_o = (size_t)(b0 + s) * OUTW;

    auto storeChunk = [&](int chIdx, int baseOff) {
        if (u3b) {
            out[outb_o + baseOff + (size_t)chIdx * 8 + cg]     = oA;
            out[outb_o + baseOff + (size_t)chIdx * 8 + 4 + cg] = oB;
        }
    };

    // out = sum over 16 unit-lanes of this sample (verified R13 chain)
    auto outdot = [&](float h) -> float {
        float pv = wl2 * h;
        pv += swzf<0x101F>(pv);                        // xor 4  (cg bit0)
        pv += swzf<0x201F>(pv);                        // xor 8  (cg bit1)
        pv += swzf<0x401F>(pv);                        // xor 16 (u bit0)
        pv += bpermf(a32, pv);                         // xor 32 (u bit1)
        return pv + blin;
    };

    // pipelined iteration t: B = {h1(t), x(t+1), h2(t-1)}
    // -> h2(t), h1(t+1), ov(t-1) (=e3[3]); builds B(t+1) with x(t+2)=xv2
    auto iterP = [&](auto Sc, float xv2) {
        constexpr int S = decltype(Sc)::v;
        const v8h Bv = makeB();
        f32x4 e0 = mfma16(A2[0], Bv, C2[0]);
        f32x4 e1 = mfma16(A2[1], Bv, C2[1]);
        f32x4 e2 = mfma16(A2[2], Bv, C2[2]);
        f32x4 e3 = mfma16(A2[3], Bv, C2[3]);
        f32x4 d0 = mfma16(A1[0], Bv, C1[0]);
        f32x4 d1 = mfma16(A1[1], Bv, C1[1]);
        f32x4 d2 = mfma16(A1[2], Bv, C1[2]);
        f32x4 d3 = mfma16(A1[3], Bv, C1[3]);

        stash(ic<(S + 7) & 7>{}, e3[3]);               // ov(t-1)

        float Q0, Q1, Q2, Q3, P0, P1, P2, P3;
        gsel(e0, e1, e2, e3, Q0, Q1, Q2, Q3);
        gsel(d0, d1, d2, d3, P0, P1, P2, P3);

        float h2n = acts(Q0, Q1, Q2, Q3, c2v);         // h2(t)
        float h1n = acts(P0, P1, P2, P3, c1v);         // h1(t+1)
        h2n = pad15 ? 0.0f : h2n;
        h1n = pad15 ? 0.0f : h1n;

        pack01(h1n, xv2);
        pack23(h2n);
    };

    // serial step (future): B = {h1(t-1), x(t)=ov(t-1), h2(t-1)}
    auto stepS = [&](auto Sc) {
        constexpr int S = decltype(Sc)::v;
        const v8h Bv = makeB();
        f32x4 d0 = mfma16(A1[0], Bv, C1[0]);
        f32x4 d1 = mfma16(A1[1], Bv, C1[1]);
        f32x4 d2 = mfma16(A1[2], Bv, C1[2]);
        f32x4 d3 = mfma16(A1[3], Bv, C1[3]);
        float P0, P1, P2, P3;
        gsel(d0, d1, d2, d3, P0, P1, P2, P3);
        float h1n = acts(P0, P1, P2, P3, c1v);
        h1n = pad15 ? 0.0f : h1n;
        pack01(h1n, 0.0f);                             // x patched after ov known

        const v8h Bv2 = makeB();                       // {h1(t), -, h2(t-1)}
        f32x4 e0 = mfma16(A2[0], Bv2, C2[0]);
        f32x4 e1 = mfma16(A2[1], Bv2, C2[1]);
        f32x4 e2 = mfma16(A2[2], Bv2, C2[2]);
        f32x4 e3 = mfma16(A2[3], Bv2, C2[3]);
        float Q0, Q1, Q2, Q3;
        gsel(e0, e1, e2, e3, Q0, Q1, Q2, Q3);
        float h2n = acts(Q0, Q1, Q2, Q3, c2v);
        h2n = pad15 ? 0.0f : h2n;

        const float ov = outdot(h2n);                  // ov(t)
        stash(ic<S>{}, ov);
        // patch x(t+1)=ov into B1.hi at u3
        const int xb = __builtin_bit_cast(int, pkrtz(0.0f, ov)) & 0xFFFF0000;
        B1 = u3b ? ((B1 & 0xFFFF) | xb) : B1;
        pack23(h2n);
    };

    // ---- prologue: h(-1)=0; h1(0); B(0) = {h1(0), x(1), 0} ----
    f32x4 xcA = *(const f32x4*)&input[xadr];
    f32x4 xcB = *(const f32x4*)&input[xadr + 4];
    {
        B0 = B2 = B3 = 0;
        B1 = u3b ? __builtin_bit_cast(int, pkrtz(0.0f, xcA[0])) : 0;  // x(0)
        const v8h Bv = makeB();
        f32x4 d0 = mfma16(A1[0], Bv, C1[0]);
        f32x4 d1 = mfma16(A1[1], Bv, C1[1]);
        f32x4 d2 = mfma16(A1[2], Bv, C1[2]);
        f32x4 d3 = mfma16(A1[3], Bv, C1[3]);
        float P0, P1, P2, P3;
        gsel(d0, d1, d2, d3, P0, P1, P2, P3);
        float h1n = acts(P0, P1, P2, P3, c1v);
        h1n = pad15 ? 0.0f : h1n;
        pack01(h1n, xcA[1]);                           // x(1)
        B2 = B3 = 0;                                   // h2(-1) = 0
    }

    // ---- main: 127 full chunks of 8 pipelined iters (t = 0..1015) ----
    #pragma unroll 1
    for (int ch = 0; ch < 127; ++ch) {
        const f32x4 xnA = *(const f32x4*)&input[xadr + (size_t)(ch + 1) * 8];
        const f32x4 xnB = *(const f32x4*)&input[xadr + (size_t)(ch + 1) * 8 + 4];
        iterP(ic<0>{}, xel<2>(xcA, xcB));
        if (ch > 0) storeChunk(ch - 1, 0);
        iterP(ic<1>{}, xel<3>(xcA, xcB));
        iterP(ic<2>{}, xel<4>(xcA, xcB));
        iterP(ic<3>{}, xel<5>(xcA, xcB));
        iterP(ic<4>{}, xel<6>(xcA, xcB));
        iterP(ic<5>{}, xel<7>(xcA, xcB));
        iterP(ic<6>{}, xnA[0]);
        iterP(ic<7>{}, xnA[1]);
        xcA = xnA; xcB = xnB;
    }

    // ---- final chunk (t = 1016..1022) + L2-only epilogue (h2(1023)) ----
    {
        iterP(ic<0>{}, xel<2>(xcA, xcB));
        storeChunk(126, 0);
        iterP(ic<1>{}, xel<3>(xcA, xcB));
        iterP(ic<2>{}, xel<4>(xcA, xcB));
        iterP(ic<3>{}, xel<5>(xcA, xcB));
        iterP(ic<4>{}, xel<6>(xcA, xcB));
        iterP(ic<5>{}, xel<7>(xcA, xcB));
        iterP(ic<6>{}, 0.0f);                          // x(1024) patched below

        // epilogue: B(1023) = {h1(1023), -, h2(1022)}
        const v8h Bv = makeB();
        f32x4 e0 = mfma16(A2[0], Bv, C2[0]);
        f32x4 e1 = mfma16(A2[1], Bv, C2[1]);
        f32x4 e2 = mfma16(A2[2], Bv, C2[2]);
        f32x4 e3 = mfma16(A2[3], Bv, C2[3]);
        stash(ic<6>{}, e3[3]);                         // ov(1022)
        float Q0, Q1, Q2, Q3;
        gsel(e0, e1, e2, e3, Q0, Q1, Q2, Q3);
        float h2n = acts(Q0, Q1, Q2, Q3, c2v);
        h2n = pad15 ? 0.0f : h2n;
        const float ov23 = outdot(h2n);                // ov(1023)
        stash(ic<7>{}, ov23);
        storeChunk(127, 0);
        // B(1024): keep regs0,1 (h1(1023)); x(1024)=ov(1023); regs2,3 <- h2(1023)
        const int xb = __builtin_bit_cast(int, pkrtz(0.0f, ov23)) & 0xFFFF0000;
        B1 = u3b ? ((B1 & 0xFFFF) | xb) : B1;
        pack23(h2n);
    }

    // ---- future: 64 serial steps, x = previous out ----
    #pragma unroll 1
    for (int fc = 0; fc < FUT / 8; ++fc) {
        unroll_for<0, 8>([&](auto sc) { stepS(sc); });
        storeChunk(fc, TMAIN);
    }
}

extern "C" void kernel_launch(void* const* d_in, const int* in_sizes, int n_in,
                              void* d_out, int out_size, void* d_ws, size_t ws_size,
                              hipStream_t stream)
{
    const float* input = (const float*)d_in[0];
    const float* W_ih1 = (const float*)d_in[1];
    const float* W_hh1 = (const float*)d_in[2];
    const float* b_ih1 = (const float*)d_in[3];
    const float* b_hh1 = (const float*)d_in[4];
    const float* W_ih2 = (const float*)d_in[5];
    const float* W_hh2 = (const float*)d_in[6];
    const float* b_ih2 = (const float*)d_in[7];
    const float* b_hh2 = (const float*)d_in[8];
    const float* W_lin = (const float*)d_in[9];
    const float* b_lin = (const float*)d_in[10];
    // d_in[11] = future (=64), compiled in as FUT

    // 4096 batches / (4 per wave * 4 waves per block) = 256 blocks
    lstm_seq_kernel<<<256, 256, 0, stream>>>(
        input, W_ih1, W_hh1, b_ih1, b_hh1,
        W_ih2, W_hh2, b_ih2, b_hh2, W_lin, b_lin,
        (float*)d_out);
}

// Round 9
// 452.059 us; speedup vs baseline: 1.1701x; 1.0348x over previous
//
#include <hip/hip_runtime.h>

#define HID   15
#define TMAIN 1024
#define FUT   64
#define OUTW  (TMAIN + FUT)   // 1088

typedef _Float16 v2h   __attribute__((ext_vector_type(2)));
typedef _Float16 v8h   __attribute__((ext_vector_type(8)));
typedef float    f32x4 __attribute__((ext_vector_type(4)));
typedef int      i32x4 __attribute__((ext_vector_type(4)));

__device__ __forceinline__ float rcp_(float x)  { return __builtin_amdgcn_rcpf(x); }
__device__ __forceinline__ float exp2_(float x) { return __builtin_amdgcn_exp2f(x); }

template<int I> struct ic { static constexpr int v = I; };
template<int J, int N, class F>
__device__ __forceinline__ void unroll_for(F&& f) {
    if constexpr (J < N) { f(ic<J>{}); unroll_for<J + 1, N>(f); }
}

// ds_swizzle BitMode: dest i reads lane ((i&and)|or)^xor within 32-lane halves.
template<int PAT>
__device__ __forceinline__ int swzi(int x) { return __builtin_amdgcn_ds_swizzle(x, PAT); }
template<int PAT>
__device__ __forceinline__ float swzf(float x) { return __int_as_float(swzi<PAT>(__float_as_int(x))); }

__device__ __forceinline__ int bpermi(int addr, int x) { return __builtin_amdgcn_ds_bpermute(addr, x); }
__device__ __forceinline__ float bpermf(int addr, float x) { return __int_as_float(bpermi(addr, __float_as_int(x))); }

// DPP: row_shl:n = 0x100+n, row_shr:n = 0x110+n (16-lane rows, bound_ctrl 0-fill)
template<int CTRL>
__device__ __forceinline__ int dppi(int x) {
    return __builtin_amdgcn_update_dpp(0, x, CTRL, 0xF, 0xF, true);
}

__device__ __forceinline__ v2h pkrtz(float lo, float hi) {
    return __builtin_bit_cast(v2h, __builtin_amdgcn_cvt_pkrtz(lo, hi));
}
__device__ __forceinline__ f32x4 mfma16(v8h a, v8h b, f32x4 c) {
    return __builtin_amdgcn_mfma_f32_16x16x32_f16(a, b, c, 0, 0, 0);
}
template<int I>
__device__ __forceinline__ float xel(const f32x4& a, const f32x4& b) {
    if constexpr (I < 4) return a[I]; else return b[I - 4];
}

// R16 = R15 (verified zero-DS main loop) + joint-rcp activations.
// R15 PMC reconciliation: VALUBusy 72% @ ~830cyc/step = ~600 issue-cyc; op
// model matches ONLY if v_exp/v_rcp are 16cyc/wave64 -> the 20 trans/step
// (320cyc) are 54% of issue.  Fix: share reciprocals algebraically:
//  c' = f*c + i*g = [c*Di*Dg + (1-Eg)*Df] / (Di*Df*Dg)   (1 rcp, was 3)
//  h  = o*tanh(c') = (1-Y) / [(1+Y)(1+Eo)]               (1 rcp, was 2)
// with Ei,Ef,Eg,Eo = exp2(pre-acts), Y = exp2(-2c'*log2e).  -3 rcp/layer
// (-48cy) +8 regular (+16cy) -> ~-80cy/step.  Exact algebra; E<=2^12,
// products <=2^36, f32-safe.  Bonus: pad lane h == 0 exactly by construction
// (c=0 -> numer=0; Y=1 -> h-numer=0, kills the ov-hijack pollution of Q3)
// -> both pad15 cndmasks dropped.
// R15 recap: chunk m = GATE m, rows = units; lane (u,4cg+s) owns unit 4u+cg
// sample s; B rebuilt in-register via 3 row-rotations + mux (slots tree,
// HW-verified); out-dot via MFMA row-15 hijack (e3[3] = ov(t-1)); x per-lane
// registers; pipeline B(t)={h1(t),x(t+1),h2(t-1)} feeds L2(t) AND L1(t+1).
__global__ __launch_bounds__(256)
__attribute__((amdgpu_waves_per_eu(1, 1)))
void lstm_seq_kernel(const float* __restrict__ input,
                     const float* __restrict__ W_ih1, const float* __restrict__ W_hh1,
                     const float* __restrict__ b_ih1, const float* __restrict__ b_hh1,
                     const float* __restrict__ W_ih2, const float* __restrict__ W_hh2,
                     const float* __restrict__ b_ih2, const float* __restrict__ b_hh2,
                     const float* __restrict__ W_lin, const float* __restrict__ b_lin,
                     float* __restrict__ out)
{
    const int tid  = threadIdx.x;
    const int wq   = tid >> 6;
    const int lane = tid & 63;
    const int u    = lane >> 4;        // K-block row / D row-group
    const int c    = lane & 15;        // MFMA col (B/D) and A-row
    const int s    = c & 3;            // sample within wave
    const int cg   = c >> 2;           // col-group == owned-unit offset
    const int b0   = (blockIdx.x * 4 + wq) * 4;

    const float L2E = 1.442695040888963f;
    const float sA[4] = {-L2E, -L2E, -2.0f * L2E, -L2E};
    const float blin = b_lin[0];

    // ---- static A fragments (chunk = gate, rows = units) + bias C ----
    v8h   A1[4], A2[4];
    f32x4 C1[4], C2[4];
    #pragma unroll
    for (int m = 0; m < 4; ++m) {
        #pragma unroll
        for (int e = 0; e < 8; ++e) {
            const int k = (e < 4) ? (4 * u + e) : (16 + 4 * u + (e - 4));
            float v1 = 0.0f, v2 = 0.0f;
            if (c < HID) {
                const int wr = m * HID + c;            // gate m, unit c
                if (k < HID)       { v1 = W_hh1[wr * HID + k]; v2 = W_ih2[wr * HID + k]; }
                else if (k == HID) { v1 = W_ih1[wr]; }                     // x slot
                else if (k >= 16 && k < 16 + HID) { v2 = W_hh2[wr * HID + (k - 16)]; }
            }
            float a2v = sA[m] * v2;
            if (c == 15 && m == 3 && k >= 16 && k < 16 + HID)
                a2v = W_lin[k - 16];                   // out-row (unscaled)
            A1[m][e] = (_Float16)(sA[m] * v1);
            A2[m][e] = (_Float16)a2v;
        }
        #pragma unroll
        for (int r = 0; r < 4; ++r) {                  // D row 4u+r = unit 4u+r, gate m
            const int U = 4 * u + r;
            float bv1 = 0.0f, bv2 = 0.0f;
            if (U < HID) {
                bv1 = sA[m] * (b_ih1[m * HID + U] + b_hh1[m * HID + U]);
                bv2 = sA[m] * (b_ih2[m * HID + U] + b_hh2[m * HID + U]);
            }
            if (u == 3 && m == 3 && r == 3) bv2 = blin;   // out-row bias
            C1[m][r] = bv1; C2[m][r] = bv2;
        }
    }

    const int   Uown = 4 * u + cg;                     // owned unit
    const float wl2  = (Uown < HID) ? W_lin[Uown] : 0.0f;

    const bool cgb0  = (cg & 1) != 0;
    const bool cgb1  = (cg & 2) != 0;
    const bool u3b   = (u == 3);
    const int  a32   = (lane ^ 32) << 2;

    int B0 = 0, B1 = 0, B2 = 0, B3 = 0;
    float c1v = 0.0f, c2v = 0.0f;
    float oA = 0.0f, oB = 0.0f;

    auto makeB = [&]() -> v8h {
        return __builtin_bit_cast(v8h, (i32x4){B0, B1, B2, B3});
    };

    // P_m = q_m[cg] (constant-index cndmask tree)
    auto gsel = [&](const f32x4& q0, const f32x4& q1, const f32x4& q2, const f32x4& q3,
                    float& g0, float& g1, float& g2, float& g3) {
        auto pick = [&](const f32x4& q) -> float {
            const float t0 = cgb0 ? q[1] : q[0];
            const float t1 = cgb0 ? q[3] : q[2];
            return cgb1 ? t1 : t0;
        };
        g0 = pick(q0); g1 = pick(q1); g2 = pick(q2); g3 = pick(q3);
    };

    // joint-rcp LSTM cell update (see header comment).  Exact algebra:
    //  i=1/(1+Ei), f=1/(1+Ef), g=(1-Eg)/(1+Eg), o=1/(1+Eo)
    //  c' = [c*Di*Dg + (1-Eg)*Df] / (Di*Df*Dg)
    //  h  = (1-Y) / [(1+Y)*(1+Eo)],  Y = 2^(-2*c'*log2e)
    auto acts = [&](float g0, float g1, float g2, float g3, float& cv) -> float {
        const float Ei = exp2_(g0);
        const float Ef = exp2_(g1);
        const float Eg = exp2_(g2);
        const float Eo = exp2_(g3);
        const float Di = 1.0f + Ei;
        const float Df = 1.0f + Ef;
        const float Dg = 1.0f + Eg;
        const float P  = Di * Dg;
        const float t  = __builtin_fmaf(-Eg, Df, Df);          // (1-Eg)*Df
        const float numer = __builtin_fmaf(cv, P, t);
        cv = numer * rcp_(P * Df);
        const float Y  = exp2_(cv * -2.885390081777927f);
        return (1.0f - Y) * rcp_((1.0f + Y) * (1.0f + Eo));
    };

    // slots: s_j = h of unit 4u+j.  R[t] = gather from col (i-4t)&15 holds
    // h[4u + ((cg-t)&3)]  =>  s_j = R[(cg-j)&3].  (HW-verified R15 tree.)
    auto slots = [&](float h, float& s0, float& s1, float& s2, float& s3) {
        const int hb = __float_as_int(h);
        const float r4  = __int_as_float(dppi<0x114>(hb) | dppi<0x10C>(hb)); // ror4
        const float r8  = __int_as_float(dppi<0x118>(hb) | dppi<0x108>(hb)); // ror8
        const float r12 = __int_as_float(dppi<0x11C>(hb) | dppi<0x104>(hb)); // ror12
        const float A0 = cgb0 ? r4  : h;
        const float A1 = cgb0 ? r12 : r8;
        const float A2 = cgb0 ? h   : r12;
        const float A3 = cgb0 ? r8  : r4;
        s0 = cgb1 ? A1 : A0;
        s1 = cgb1 ? A3 : A2;
        s2 = cgb1 ? A0 : A1;
        s3 = cgb1 ? A2 : A3;
    };

    auto pack01 = [&](float h1n, float xv) {           // B regs 0,1 <- h1 (+x at u3)
        float s0, s1, s2, s3; slots(h1n, s0, s1, s2, s3);
        B0 = __builtin_bit_cast(int, pkrtz(s0, s1));
        B1 = __builtin_bit_cast(int, pkrtz(s2, u3b ? xv : s3));
    };
    auto pack23 = [&](float h2n) {                     // B regs 2,3 <- h2
        float s0, s1, s2, s3; slots(h2n, s0, s1, s2, s3);
        B2 = __builtin_bit_cast(int, pkrtz(s0, s1));
        B3 = __builtin_bit_cast(int, pkrtz(s2, s3));
    };

    auto stash = [&](auto SigC, float ov) {            // slot sig -> oA/oB at cg==sig&3
        constexpr int SIG = decltype(SigC)::v;
        const bool own = (cg == (SIG & 3));
        if constexpr (SIG < 4) oA = own ? ov : oA;
        else                   oB = own ? ov : oB;
    };

    const size_t xadr   = (size_t)(b0 + s) * TMAIN;
    const size_t outb_o = (size_t)(b0 + s) * OUTW;

    auto storeChunk = [&](int chIdx, int baseOff) {
        if (u3b) {
            out[outb_o + baseOff + (size_t)chIdx * 8 + cg]     = oA;
            out[outb_o + baseOff + (size_t)chIdx * 8 + 4 + cg] = oB;
        }
    };

    // out = sum over 16 unit-lanes of this sample (verified chain)
    auto outdot = [&](float h) -> float {
        float pv = wl2 * h;
        pv += swzf<0x101F>(pv);                        // xor 4  (cg bit0)
        pv += swzf<0x201F>(pv);                        // xor 8  (cg bit1)
        pv += swzf<0x401F>(pv);                        // xor 16 (u bit0)
        pv += bpermf(a32, pv);                         // xor 32 (u bit1)
        return pv + blin;
    };

    // pipelined iteration t: B = {h1(t), x(t+1), h2(t-1)}
    // -> h2(t), h1(t+1), ov(t-1) (=e3[3]); builds B(t+1) with x(t+2)=xv2
    auto iterP = [&](auto Sc, float xv2) {
        constexpr int S = decltype(Sc)::v;
        const v8h Bv = makeB();
        f32x4 e0 = mfma16(A2[0], Bv, C2[0]);
        f32x4 e1 = mfma16(A2[1], Bv, C2[1]);
        f32x4 e2 = mfma16(A2[2], Bv, C2[2]);
        f32x4 e3 = mfma16(A2[3], Bv, C2[3]);
        f32x4 d0 = mfma16(A1[0], Bv, C1[0]);
        f32x4 d1 = mfma16(A1[1], Bv, C1[1]);
        f32x4 d2 = mfma16(A1[2], Bv, C1[2]);
        f32x4 d3 = mfma16(A1[3], Bv, C1[3]);

        stash(ic<(S + 7) & 7>{}, e3[3]);               // ov(t-1)

        float Q0, Q1, Q2, Q3, P0, P1, P2, P3;
        gsel(e0, e1, e2, e3, Q0, Q1, Q2, Q3);
        gsel(d0, d1, d2, d3, P0, P1, P2, P3);

        const float h2n = acts(Q0, Q1, Q2, Q3, c2v);   // h2(t)   (pad: exact 0)
        const float h1n = acts(P0, P1, P2, P3, c1v);   // h1(t+1) (pad: exact 0)

        pack01(h1n, xv2);
        pack23(h2n);
    };

    // serial step (future): B = {h1(t-1), x(t)=ov(t-1), h2(t-1)}
    auto stepS = [&](auto Sc) {
        constexpr int S = decltype(Sc)::v;
        const v8h Bv = makeB();
        f32x4 d0 = mfma16(A1[0], Bv, C1[0]);
        f32x4 d1 = mfma16(A1[1], Bv, C1[1]);
        f32x4 d2 = mfma16(A1[2], Bv, C1[2]);
        f32x4 d3 = mfma16(A1[3], Bv, C1[3]);
        float P0, P1, P2, P3;
        gsel(d0, d1, d2, d3, P0, P1, P2, P3);
        const float h1n = acts(P0, P1, P2, P3, c1v);
        pack01(h1n, 0.0f);                             // x patched after ov known

        const v8h Bv2 = makeB();                       // {h1(t), -, h2(t-1)}
        f32x4 e0 = mfma16(A2[0], Bv2, C2[0]);
        f32x4 e1 = mfma16(A2[1], Bv2, C2[1]);
        f32x4 e2 = mfma16(A2[2], Bv2, C2[2]);
        f32x4 e3 = mfma16(A2[3], Bv2, C2[3]);
        float Q0, Q1, Q2, Q3;
        gsel(e0, e1, e2, e3, Q0, Q1, Q2, Q3);
        const float h2n = acts(Q0, Q1, Q2, Q3, c2v);

        const float ov = outdot(h2n);                  // ov(t)
        stash(ic<S>{}, ov);
        // patch x(t+1)=ov into B1.hi at u3
        const int xb = __builtin_bit_cast(int, pkrtz(0.0f, ov)) & 0xFFFF0000;
        B1 = u3b ? ((B1 & 0xFFFF) | xb) : B1;
        pack23(h2n);
    };

    // ---- prologue: h(-1)=0; h1(0); B(0) = {h1(0), x(1), 0} ----
    f32x4 xcA = *(const f32x4*)&input[xadr];
    f32x4 xcB = *(const f32x4*)&input[xadr + 4];
    {
        B0 = B2 = B3 = 0;
        B1 = u3b ? __builtin_bit_cast(int, pkrtz(0.0f, xcA[0])) : 0;  // x(0)
        const v8h Bv = makeB();
        f32x4 d0 = mfma16(A1[0], Bv, C1[0]);
        f32x4 d1 = mfma16(A1[1], Bv, C1[1]);
        f32x4 d2 = mfma16(A1[2], Bv, C1[2]);
        f32x4 d3 = mfma16(A1[3], Bv, C1[3]);
        float P0, P1, P2, P3;
        gsel(d0, d1, d2, d3, P0, P1, P2, P3);
        const float h1n = acts(P0, P1, P2, P3, c1v);
        pack01(h1n, xcA[1]);                           // x(1)
        B2 = B3 = 0;                                   // h2(-1) = 0
    }

    // ---- main: 127 full chunks of 8 pipelined iters (t = 0..1015) ----
    #pragma unroll 1
    for (int ch = 0; ch < 127; ++ch) {
        const f32x4 xnA = *(const f32x4*)&input[xadr + (size_t)(ch + 1) * 8];
        const f32x4 xnB = *(const f32x4*)&input[xadr + (size_t)(ch + 1) * 8 + 4];
        iterP(ic<0>{}, xel<2>(xcA, xcB));
        if (ch > 0) storeChunk(ch - 1, 0);
        iterP(ic<1>{}, xel<3>(xcA, xcB));
        iterP(ic<2>{}, xel<4>(xcA, xcB));
        iterP(ic<3>{}, xel<5>(xcA, xcB));
        iterP(ic<4>{}, xel<6>(xcA, xcB));
        iterP(ic<5>{}, xel<7>(xcA, xcB));
        iterP(ic<6>{}, xnA[0]);
        iterP(ic<7>{}, xnA[1]);
        xcA = xnA; xcB = xnB;
    }

    // ---- final chunk (t = 1016..1022) + L2-only epilogue (h2(1023)) ----
    {
        iterP(ic<0>{}, xel<2>(xcA, xcB));
        storeChunk(126, 0);
        iterP(ic<1>{}, xel<3>(xcA, xcB));
        iterP(ic<2>{}, xel<4>(xcA, xcB));
        iterP(ic<3>{}, xel<5>(xcA, xcB));
        iterP(ic<4>{}, xel<6>(xcA, xcB));
        iterP(ic<5>{}, xel<7>(xcA, xcB));
        iterP(ic<6>{}, 0.0f);                          // x(1024) patched below

        // epilogue: B(1023) = {h1(1023), -, h2(1022)}
        const v8h Bv = makeB();
        f32x4 e0 = mfma16(A2[0], Bv, C2[0]);
        f32x4 e1 = mfma16(A2[1], Bv, C2[1]);
        f32x4 e2 = mfma16(A2[2], Bv, C2[2]);
        f32x4 e3 = mfma16(A2[3], Bv, C2[3]);
        stash(ic<6>{}, e3[3]);                         // ov(1022)
        float Q0, Q1, Q2, Q3;
        gsel(e0, e1, e2, e3, Q0, Q1, Q2, Q3);
        const float h2n = acts(Q0, Q1, Q2, Q3, c2v);
        const float ov23 = outdot(h2n);                // ov(1023)
        stash(ic<7>{}, ov23);
        storeChunk(127, 0);
        // B(1024): keep regs0,1 (h1(1023)); x(1024)=ov(1023); regs2,3 <- h2(1023)
        const int xb = __builtin_bit_cast(int, pkrtz(0.0f, ov23)) & 0xFFFF0000;
        B1 = u3b ? ((B1 & 0xFFFF) | xb) : B1;
        pack23(h2n);
    }

    // ---- future: 64 serial steps, x = previous out ----
    #pragma unroll 1
    for (int fc = 0; fc < FUT / 8; ++fc) {
        unroll_for<0, 8>([&](auto sc) { stepS(sc); });
        storeChunk(fc, TMAIN);
    }
}

extern "C" void kernel_launch(void* const* d_in, const int* in_sizes, int n_in,
                              void* d_out, int out_size, void* d_ws, size_t ws_size,
                              hipStream_t stream)
{
    const float* input = (const float*)d_in[0];
    const float* W_ih1 = (const float*)d_in[1];
    const float* W_hh1 = (const float*)d_in[2];
    const float* b_ih1 = (const float*)d_in[3];
    const float* b_hh1 = (const float*)d_in[4];
    const float* W_ih2 = (const float*)d_in[5];
    const float* W_hh2 = (const float*)d_in[6];
    const float* b_ih2 = (const float*)d_in[7];
    const float* b_hh2 = (const float*)d_in[8];
    const float* W_lin = (const float*)d_in[9];
    const float* b_lin = (const float*)d_in[10];
    // d_in[11] = future (=64), compiled in as FUT

    // 4096 batches / (4 per wave * 4 waves per block) = 256 blocks
    lstm_seq_kernel<<<256, 256, 0, stream>>>(
        input, W_ih1, W_hh1, b_ih1, b_hh1,
        W_ih2, W_hh2, b_ih2, b_hh2, W_lin, b_lin,
        (float*)d_out);
}